// Round 13
// baseline (197.755 us; speedup 1.0000x reference)
//
#include <hip/hip_runtime.h>
#include <cstdint>
#include <cstddef>

#define Bn 64
#define Tn 2048
#define Un 512
#define QSn 512
#define MSn 512
#define TCH 128
#define NCHK 16   // chunks per batch = Tn/TCH
#define NKT 16    // K-tiles: 512 / 32

using f32x16 = __attribute__((ext_vector_type(16))) float;
using bf16x8 = __attribute__((ext_vector_type(8))) short;

__device__ __forceinline__ unsigned short f2bf(float x) {
    unsigned int u = __float_as_uint(x);
    u += 0x7FFFu + ((u >> 16) & 1u);
    return (unsigned short)(u >> 16);
}

__device__ __forceinline__ unsigned int pk2bf(float lo, float hi) {
    unsigned int r;
    asm("v_cvt_pk_bf16_f32 %0, %1, %2" : "=v"(r) : "v"(lo), "v"(hi));
    return r;
}

__device__ __forceinline__ bf16x8 cvt8(float4 a, float4 b) {
    union { unsigned int u[4]; bf16x8 v; } r;
    r.u[0] = pk2bf(a.x, a.y);
    r.u[1] = pk2bf(a.z, a.w);
    r.u[2] = pk2bf(b.x, b.y);
    r.u[3] = pk2bf(b.z, b.w);
    return r.v;
}

__device__ __forceinline__ float tanh_fast(float x) {
    float e = exp2f(x * 2.885390043258667f);   // e^{2x}
    return 1.f - 2.f * __builtin_amdgcn_rcpf(e + 1.f);
}

// async global->LDS, 16B per lane; LDS dest = wave-uniform base + lane*16
#define GLOAD(G, L) __builtin_amdgcn_global_load_lds( \
    (const __attribute__((address_space(1))) void*)(G), \
    (__attribute__((address_space(3))) void*)(L), 16, 0, 0)

#define SB() __builtin_amdgcn_sched_barrier(0)

// ---------------- Wm f32 -> bf16 pre-convert ----------------
__global__ __launch_bounds__(256) void cvt_kernel(const float* __restrict__ src,
                                                  unsigned short* __restrict__ dst) {
    int i = blockIdx.x * 256 + threadIdx.x;  // one float4 per thread
    float4 v = *(const float4*)(src + (size_t)i * 4);
    ushort4 h = { f2bf(v.x), f2bf(v.y), f2bf(v.z), f2bf(v.w) };
    *(ushort4*)&dst[(size_t)i * 4] = h;
}

// ---------------- pq = query @ Wq^T : [B,U] ----------------
__global__ __launch_bounds__(128) void pq_kernel(const float* __restrict__ query,
                                                 const float* __restrict__ Wq,
                                                 float* __restrict__ pq) {
    __shared__ float ql[QSn];
    const int b = blockIdx.x;
    const int quad = blockIdx.y;
    const int tid = threadIdx.x;
    for (int i = tid; i < QSn; i += 128) ql[i] = query[(size_t)b * QSn + i];
    __syncthreads();
    const int u = quad * 128 + tid;
    const float* w = Wq + (size_t)u * QSn;
    float a0 = 0.f, a1 = 0.f;
    #pragma unroll 4
    for (int k = 0; k < QSn; k += 8) {
        float4 w0 = *(const float4*)(w + k);
        float4 w1 = *(const float4*)(w + k + 4);
        float4 q0 = *(const float4*)(ql + k);
        float4 q1 = *(const float4*)(ql + k + 4);
        a0 += w0.x * q0.x + w0.y * q0.y + w0.z * q0.z + w0.w * q0.w;
        a1 += w1.x * q1.x + w1.y * q1.y + w1.z * q1.z + w1.w * q1.w;
    }
    pq[(size_t)b * Un + u] = a0 + a1;
}

// ---------------- fused score+softmax+context (v13: all-GLOAD, race-free) ----
// Block = (b, 128-t chunk), 512 thr = 8 waves. Wave w owns u [w*64, w*64+64);
// acc[4 mf][2 nf] covers 128t x 64u. BK=32, NKT=16. ONE barrier per iter.
// A: keys f32, 16KB/tile, QUAD-buffered via GLOAD (2 per wave/iter), issued
//    2 iters ahead. WAR-safe: Ah[(kt+2)&3]'s last readers ran at iter kt-2 and
//    passed the iter kt-1 barrier before the GLOAD at iter kt is issued.
//    f32->bf16 conversion on the READ side (cvt_pk after ds_read).
// B: Wm bf16, wave-private 4KB dbuf (4 GLOADs/iter), issued 1 iter ahead;
//    WAR-safe by program order within the wave.
// FIFO per wave/iter: B(kt+1)[4] then A(kt+2)[2]; vmcnt(8) at barrier drains
// exactly A(kt)+B(kt): A slack = 2 iters (HBM-safe), B = 1 iter (L2-safe).
__global__ __launch_bounds__(512, 2) void fused_kernel(const float* __restrict__ keys,
                                                       const unsigned short* __restrict__ WmB,
                                                       const float* __restrict__ pq,
                                                       const float* __restrict__ Wa,
                                                       float* __restrict__ score_out,
                                                       float* __restrict__ pm,
                                                       float* __restrict__ pl,
                                                       float* __restrict__ pctx) {
    __shared__ __align__(16) float Ah[4][TCH * 32];               // 64 KB (f32)
    __shared__ __align__(16) unsigned short Bh[8][2][64 * 32];    // 64 KB
    __shared__ float sc_lds[8][TCH];                              // 4 KB
    __shared__ float stot[TCH];
    __shared__ float wexp[TCH];
    __shared__ float redm[2], reds[2];

    const int tid = threadIdx.x;
    const int lane = tid & 63;
    const int w = tid >> 6;
    const int lc = lane & 31;
    const int l5 = lane >> 5;
    const int b = blockIdx.y;
    const int chunk = blockIdx.x;
    const int t0 = chunk * TCH;

    const float* keyBase = keys + (size_t)(b * Tn + t0) * MSn;

    // ---- A staging source offsets (swizzle folded into global address).
    // GLOAD j of wave w -> linear LDS bytes w*2048 + j*1024 + lane*16:
    // rowpair rp = w*8 + j*4 + (lane>>4), phys granule = lane&15 (16B of 4 f32)
    // logical g = phys ^ ((rp&7)<<1); row = rp*2 + (g&1); kf32 = (g>>1)*4.
    int aoff0, aoff1;
    {
        int rpl0 = (lane >> 4);            // j=0
        int g0 = (lane & 15) ^ ((rpl0 & 7) << 1);
        aoff0 = (w * 16 + rpl0 * 2 + (g0 & 1)) * MSn + (g0 >> 1) * 4;
        int rpl1 = 4 + (lane >> 4);        // j=1
        int g1 = (lane & 15) ^ ((rpl1 & 7) << 1);
        aoff1 = (w * 16 + rpl1 * 2 + (g1 & 1)) * MSn + (g1 >> 1) * 4;
    }

    // ---- B staging source (R11-verbatim swizzle; measured 0 conflicts).
    // GLOAD j -> rp = j*8 + (lane>>3), phys = lane&7; g = phys ^ (rp&7).
    const int bg = (lane & 7) ^ ((lane >> 3) & 7);
    const size_t bsrc0 = (size_t)(w * 64 + (((lane >> 3) << 1) | (bg & 1))) * MSn + (bg >> 1) * 8;
    const unsigned short* gBw = WmB + bsrc0;
    char* bDst = (char*)&Bh[w][0][0];

    f32x16 acc[4][2];
    #pragma unroll
    for (int mf = 0; mf < 4; ++mf)
        #pragma unroll
        for (int nf = 0; nf < 2; ++nf)
            #pragma unroll
            for (int r = 0; r < 16; ++r) acc[mf][nf][r] = 0.f;

    #define STAGE_B(KT, BUF) do { \
        const unsigned short* gb_ = gBw + (KT) * 32; \
        char* d_ = bDst + (BUF) * 4096; \
        GLOAD(gb_,                       d_); \
        GLOAD(gb_ + (size_t)16 * MSn,    d_ + 1024); \
        GLOAD(gb_ + (size_t)32 * MSn,    d_ + 2048); \
        GLOAD(gb_ + (size_t)48 * MSn,    d_ + 3072); } while (0)

    #define STAGE_A(KT, BUF) do { \
        char* d_ = (char*)&Ah[BUF][0] + w * 2048; \
        GLOAD(keyBase + (KT) * 32 + aoff0, d_); \
        GLOAD(keyBase + (KT) * 32 + aoff1, d_ + 1024); } while (0)

    // ---- prologue: B(0) -> buf0; A(0) -> Ah[0]; A(1) -> Ah[1]
    STAGE_B(0, 0);
    SB();
    STAGE_A(0, 0);
    SB();
    STAGE_A(1, 1);
    SB();

    #pragma unroll
    for (int kt = 0; kt < NKT; ++kt) {
        // 1) issue next loads: B(kt+1), then A(kt+2)
        if (kt < NKT - 1) { STAGE_B(kt + 1, (kt + 1) & 1); SB(); }
        if (kt < NKT - 2) { STAGE_A(kt + 2, (kt + 2) & 3); SB(); }

        // 2) counted drain of exactly A(kt)+B(kt), then barrier
        if (kt < NKT - 2) {
            asm volatile("s_waitcnt vmcnt(8) lgkmcnt(0)" ::: "memory");
        } else if (kt == NKT - 2) {
            asm volatile("s_waitcnt vmcnt(6) lgkmcnt(0)" ::: "memory");
        } else {
            asm volatile("s_waitcnt vmcnt(0) lgkmcnt(0)" ::: "memory");
        }
        __builtin_amdgcn_s_barrier();
        SB();

        // 3) MFMA phase: A from shared f32 LDS (cvt on read), B wave-private
        {
            const float* lA = &Ah[kt & 3][0];
            const unsigned short* lB = &Bh[w][kt & 1][0];
            #pragma unroll
            for (int ks = 0; ks < 2; ++ks) {
                bf16x8 af[4];
                #pragma unroll
                for (int mf = 0; mf < 4; ++mf) {
                    int rp = mf * 16 + (lc >> 1);
                    int kg0 = (ks * 2 + l5) * 2;
                    int p0 = ((kg0 << 1) | (lc & 1)) ^ (((lc >> 1) & 7) << 1);
                    int p1 = (((kg0 + 1) << 1) | (lc & 1)) ^ (((lc >> 1) & 7) << 1);
                    float4 f0 = *(const float4*)&lA[rp * 64 + p0 * 4];
                    float4 f1 = *(const float4*)&lA[rp * 64 + p1 * 4];
                    af[mf] = cvt8(f0, f1);
                }
                bf16x8 bfr[2];
                #pragma unroll
                for (int nf = 0; nf < 2; ++nf) {
                    int ru = nf * 32 + lc;
                    int gp = (((ks * 2 + l5) << 1) | (ru & 1)) ^ ((ru >> 1) & 7);
                    bfr[nf] = *(const bf16x8*)&lB[(ru >> 1) * 64 + gp * 8];
                }
                #pragma unroll
                for (int mf = 0; mf < 4; ++mf)
                    #pragma unroll
                    for (int nf = 0; nf < 2; ++nf)
                        acc[mf][nf] = __builtin_amdgcn_mfma_f32_32x32x16_bf16(
                            af[mf], bfr[nf], acc[mf][nf], 0, 0, 0);
            }
        }
    }
    #undef STAGE_A
    #undef STAGE_B

    // ---- epilogue: per-wave partial score over its 64 u
    // C layout: col(u)=lc, row(t) = mf*32 + (r&3) + 8*(r>>2) + 4*l5
    float pqv[2], wav[2];
    #pragma unroll
    for (int nf = 0; nf < 2; ++nf) {
        int u = w * 64 + nf * 32 + lc;
        pqv[nf] = pq[(size_t)b * Un + u];
        wav[nf] = Wa[u];
    }
    #pragma unroll
    for (int mf = 0; mf < 4; ++mf) {
        #pragma unroll
        for (int r = 0; r < 16; ++r) {
            float s = tanh_fast(acc[mf][0][r] + pqv[0]) * wav[0]
                    + tanh_fast(acc[mf][1][r] + pqv[1]) * wav[1];
            s += __shfl_xor(s, 16);
            s += __shfl_xor(s, 8);
            s += __shfl_xor(s, 4);
            s += __shfl_xor(s, 2);
            s += __shfl_xor(s, 1);
            if (lc == 0)
                sc_lds[w][mf * 32 + (r & 3) + 8 * (r >> 2) + 4 * l5] = s;
        }
    }
    __syncthreads();

    // ---- combine 8 wave-partials; write raw scores
    float v = 0.f;
    if (tid < TCH) {
        v = ((sc_lds[0][tid] + sc_lds[1][tid]) + (sc_lds[2][tid] + sc_lds[3][tid]))
          + ((sc_lds[4][tid] + sc_lds[5][tid]) + (sc_lds[6][tid] + sc_lds[7][tid]));
        stot[tid] = v;
        score_out[(size_t)b * Tn + t0 + tid] = v;
    }

    // ---- chunk softmax partials (threads 0..127 = waves 0,1)
    if (tid < TCH) {
        float mx = v;
        #pragma unroll
        for (int off = 32; off; off >>= 1) mx = fmaxf(mx, __shfl_xor(mx, off));
        if (lane == 0) redm[tid >> 6] = mx;
    }
    __syncthreads();
    const float M = fmaxf(redm[0], redm[1]);
    if (tid < TCH) {
        float e = __expf(v - M);
        wexp[tid] = e;
        float sum = e;
        #pragma unroll
        for (int off = 32; off; off >>= 1) sum += __shfl_xor(sum, off);
        if (lane == 0) reds[tid >> 6] = sum;
    }
    __syncthreads();
    if (tid == 0) {
        pm[b * NCHK + chunk] = M;
        pl[b * NCHK + chunk] = reds[0] + reds[1];
    }

    // ---- ctx partial: thread owns 1 m-col; keys rows re-read (L2/L3-hot)
    const float* kp = keyBase + tid;
    float cx = 0.f;
    #pragma unroll 8
    for (int t = 0; t < TCH; ++t)
        cx += wexp[t] * kp[(size_t)t * MSn];
    pctx[((size_t)(b * NCHK + chunk)) * MSn + tid] = cx;
}

// ---------------- merge chunk partials -> total_context ----------------
__global__ __launch_bounds__(512) void merge_kernel(const float* __restrict__ pm,
                                                    const float* __restrict__ pl,
                                                    const float* __restrict__ pctx,
                                                    float* __restrict__ ctx) {
    __shared__ float sm[NCHK], sl[NCHK];
    const int b = blockIdx.x, tid = threadIdx.x;
    if (tid < NCHK) {
        sm[tid] = pm[b * NCHK + tid];
        sl[tid] = pl[b * NCHK + tid];
    }
    __syncthreads();
    float M = -1e30f;
    #pragma unroll
    for (int c = 0; c < NCHK; ++c) M = fmaxf(M, sm[c]);
    float L = 0.f;
    #pragma unroll
    for (int c = 0; c < NCHK; ++c) L += sl[c] * __expf(sm[c] - M);
    const float inv = 1.f / L;
    float acc = 0.f;
    #pragma unroll
    for (int c = 0; c < NCHK; ++c)
        acc += __expf(sm[c] - M) * pctx[((size_t)(b * NCHK + c)) * MSn + tid];
    ctx[(size_t)b * MSn + tid] = acc * inv;
}

extern "C" void kernel_launch(void* const* d_in, const int* in_sizes, int n_in,
                              void* d_out, int out_size, void* d_ws, size_t ws_size,
                              hipStream_t stream) {
    const float* query = (const float*)d_in[0];
    const float* keys  = (const float*)d_in[1];
    const float* Wq    = (const float*)d_in[2];
    const float* Wm    = (const float*)d_in[3];
    const float* Wa    = (const float*)d_in[4];

    float* ctx_out   = (float*)d_out;                    // [64][512]
    float* score_out = (float*)d_out + (size_t)Bn * MSn; // [64][2048]

    char* ws = (char*)d_ws;
    float* ws_pq   = (float*)(ws);                       // 128 KB
    unsigned short* ws_wmbf = (unsigned short*)(ws + 131072);  // 512 KB
    float* ws_pm   = (float*)(ws + 655360);              // 4 KB
    float* ws_pl   = (float*)(ws + 659456);              // 4 KB
    float* ws_pctx = (float*)(ws + 663552);              // 2 MB [64][16][512]

    cvt_kernel<<<(Un * MSn / 4) / 256, 256, 0, stream>>>(Wm, ws_wmbf);
    pq_kernel<<<dim3(Bn, 4), 128, 0, stream>>>(query, Wq, ws_pq);
    fused_kernel<<<dim3(NCHK, Bn), 512, 0, stream>>>(keys, ws_wmbf, ws_pq, Wa,
                                                     score_out, ws_pm, ws_pl, ws_pctx);
    merge_kernel<<<Bn, 512, 0, stream>>>(ws_pm, ws_pl, ws_pctx, ctx_out);
}

// Round 14
// 191.038 us; speedup vs baseline: 1.0352x; 1.0352x over previous
//
#include <hip/hip_runtime.h>
#include <cstdint>
#include <cstddef>

#define Bn 64
#define Tn 2048
#define Un 512
#define QSn 512
#define MSn 512
#define TCH 64
#define NCH 32   // chunks per batch = Tn/TCH
#define NKT 16   // K-tiles: 512 / 32

using f32x16 = __attribute__((ext_vector_type(16))) float;
using bf16x8 = __attribute__((ext_vector_type(8))) short;

__device__ __forceinline__ unsigned short f2bf(float x) {
    unsigned int u = __float_as_uint(x);
    u += 0x7FFFu + ((u >> 16) & 1u);
    return (unsigned short)(u >> 16);
}

__device__ __forceinline__ unsigned int pk2bf(float lo, float hi) {
    unsigned int r;
    asm("v_cvt_pk_bf16_f32 %0, %1, %2" : "=v"(r) : "v"(lo), "v"(hi));
    return r;
}

__device__ __forceinline__ bf16x8 cvt8(float4 a, float4 b) {
    union { unsigned int u[4]; bf16x8 v; } r;
    r.u[0] = pk2bf(a.x, a.y);
    r.u[1] = pk2bf(a.z, a.w);
    r.u[2] = pk2bf(b.x, b.y);
    r.u[3] = pk2bf(b.z, b.w);
    return r.v;
}

__device__ __forceinline__ float tanh_fast(float x) {
    float e = exp2f(x * 2.885390043258667f);   // e^{2x}
    return 1.f - 2.f * __builtin_amdgcn_rcpf(e + 1.f);
}

// async global->LDS, 16B per lane; LDS dest = wave-uniform base + lane*16
#define GLOAD(G, L) __builtin_amdgcn_global_load_lds( \
    (const __attribute__((address_space(1))) void*)(G), \
    (__attribute__((address_space(3))) void*)(L), 16, 0, 0)

#define SB() __builtin_amdgcn_sched_barrier(0)

// phase-end: counted vmcnt (never drain in-flight prefetch), lgkm, barrier
#define PHASE_END(N) do { \
    asm volatile("s_waitcnt vmcnt(" #N ") lgkmcnt(0)" ::: "memory"); \
    __builtin_amdgcn_s_barrier(); \
    SB(); } while (0)

// ---------------- Wm f32 -> bf16 pre-convert ----------------
__global__ __launch_bounds__(256) void cvt_kernel(const float* __restrict__ src,
                                                  unsigned short* __restrict__ dst) {
    int i = blockIdx.x * 256 + threadIdx.x;  // one float4 per thread
    float4 v = *(const float4*)(src + (size_t)i * 4);
    ushort4 h = { f2bf(v.x), f2bf(v.y), f2bf(v.z), f2bf(v.w) };
    *(ushort4*)&dst[(size_t)i * 4] = h;
}

// ---------------- pq = query @ Wq^T : [B,U] ----------------
__global__ __launch_bounds__(128) void pq_kernel(const float* __restrict__ query,
                                                 const float* __restrict__ Wq,
                                                 float* __restrict__ pq) {
    __shared__ float ql[QSn];
    const int b = blockIdx.x;
    const int quad = blockIdx.y;
    const int tid = threadIdx.x;
    for (int i = tid; i < QSn; i += 128) ql[i] = query[(size_t)b * QSn + i];
    __syncthreads();
    const int u = quad * 128 + tid;
    const float* w = Wq + (size_t)u * QSn;
    float a0 = 0.f, a1 = 0.f;
    #pragma unroll 4
    for (int k = 0; k < QSn; k += 8) {
        float4 w0 = *(const float4*)(w + k);
        float4 w1 = *(const float4*)(w + k + 4);
        float4 q0 = *(const float4*)(ql + k);
        float4 q1 = *(const float4*)(ql + k + 4);
        a0 += w0.x * q0.x + w0.y * q0.y + w0.z * q0.z + w0.w * q0.w;
        a1 += w1.x * q1.x + w1.y * q1.y + w1.z * q1.z + w1.w * q1.w;
    }
    pq[(size_t)b * Un + u] = a0 + a1;
}

// ---------------- fused score+softmax+context (v14: 2-phase ring) ----------
// Block = (b, 64-t chunk), 256 thr = 4 waves. Per kt (BK=32): 2 phases
// (uh = 256-u halves). Wave tile 64t x 64u per phase -> acc[2][2][2] (128).
// B: wave-private 64-row slice of each 256x32 tile, ring-4 LDS (16KB each),
//    issued @phase p for consumption @p+2 (1.5-phase slack >= L2 latency).
// A: f32 regs (depth-2 slots) -> cvt_pk -> bf16 LDS dbuf; shared, 1 barrier
//    per phase orders it. pq/Wa loads HOISTED into the counted prologue so
//    the compiler cannot inject vmem into the counted-vmcnt FIFO (R12 race).
// Hand-simulated FIFO: every phase ends vmcnt(6); tail 4/4/0.
__global__ __launch_bounds__(256, 2) void fused_kernel(const float* __restrict__ keys,
                                                       const unsigned short* __restrict__ WmB,
                                                       const float* __restrict__ pq,
                                                       const float* __restrict__ Wa,
                                                       float* __restrict__ score_out,
                                                       float* __restrict__ pm,
                                                       float* __restrict__ pl,
                                                       float* __restrict__ pctx) {
    __shared__ __align__(16) unsigned short Ah[2][TCH * 32];      // 8 KB
    __shared__ __align__(16) unsigned short Bh[4][256 * 32];      // 64 KB
    __shared__ float sc_lds[4][TCH];
    __shared__ float stot[TCH];
    __shared__ float wexp[TCH];

    const int tid = threadIdx.x;
    const int lane = tid & 63;
    const int w = tid >> 6;
    const int lc = lane & 31;
    const int l5 = lane >> 5;
    const int b = blockIdx.y;
    const int chunk = blockIdx.x;
    const int t0 = chunk * TCH;

    // ---- A staging: thread owns (row ar = tid>>2, granule akg = tid&3)
    const int ar = tid >> 2;
    const int akg = tid & 3;
    const int awof = (tid >> 3) * 64 +
                     ((((akg << 1) | (ar & 1)) ^ ((tid >> 3) & 7)) * 8);
    const float* gA = keys + ((size_t)b * Tn + t0 + ar) * MSn + akg * 8;

    // ---- B staging source (R11 zero-conflict swizzle folded into source)
    const int bg = (lane & 7) ^ ((lane >> 3) & 7);
    const int brow2 = ((lane >> 3) << 1) | (bg & 1);
    const unsigned short* gBt = WmB + (size_t)(w * 64 + brow2) * MSn + (bg >> 1) * 8;

    #define STAGE_B(KT, UH, BUF) do { \
        const unsigned short* s_ = gBt + (size_t)((UH) * 256) * MSn + (KT) * 32; \
        char* d_ = (char*)&Bh[BUF][0] + w * 4096; \
        GLOAD(s_,                    d_); \
        GLOAD(s_ + (size_t)16 * MSn, d_ + 1024); \
        GLOAD(s_ + (size_t)32 * MSn, d_ + 2048); \
        GLOAD(s_ + (size_t)48 * MSn, d_ + 3072); } while (0)

    f32x16 acc[2][2][2];
    #pragma unroll
    for (int uh = 0; uh < 2; ++uh)
        #pragma unroll
        for (int mf = 0; mf < 2; ++mf)
            #pragma unroll
            for (int nf = 0; nf < 2; ++nf)
                #pragma unroll
                for (int r = 0; r < 16; ++r) acc[uh][mf][nf][r] = 0.f;

    bf16x8 af[2][2];   // [mf][ks], read once per kt at the even phase

    #define READ_AF(CUR) do { \
        const unsigned short* lA_ = &Ah[CUR][0]; \
        _Pragma("unroll") \
        for (int ks = 0; ks < 2; ++ks) \
            _Pragma("unroll") \
            for (int mf = 0; mf < 2; ++mf) { \
                int r_ = mf * 32 + lc; \
                int gp_ = (((ks * 2 + l5) << 1) | (r_ & 1)) ^ ((r_ >> 1) & 7); \
                af[mf][ks] = *(const bf16x8*)&lA_[(r_ >> 1) * 64 + gp_ * 8]; \
            } } while (0)

    #define MFMA_PH(UH, BUF) do { \
        const unsigned short* lB_ = &Bh[BUF][0]; \
        _Pragma("unroll") \
        for (int ks = 0; ks < 2; ++ks) { \
            bf16x8 bfr0, bfr1; \
            { int ru_ = w * 64 + lc; \
              int gp_ = (((ks * 2 + l5) << 1) | (ru_ & 1)) ^ ((ru_ >> 1) & 7); \
              bfr0 = *(const bf16x8*)&lB_[(ru_ >> 1) * 64 + gp_ * 8]; } \
            { int ru_ = w * 64 + 32 + lc; \
              int gp_ = (((ks * 2 + l5) << 1) | (ru_ & 1)) ^ ((ru_ >> 1) & 7); \
              bfr1 = *(const bf16x8*)&lB_[(ru_ >> 1) * 64 + gp_ * 8]; } \
            acc[UH][0][0] = __builtin_amdgcn_mfma_f32_32x32x16_bf16(af[0][ks], bfr0, acc[UH][0][0], 0, 0, 0); \
            acc[UH][0][1] = __builtin_amdgcn_mfma_f32_32x32x16_bf16(af[0][ks], bfr1, acc[UH][0][1], 0, 0, 0); \
            acc[UH][1][0] = __builtin_amdgcn_mfma_f32_32x32x16_bf16(af[1][ks], bfr0, acc[UH][1][0], 0, 0, 0); \
            acc[UH][1][1] = __builtin_amdgcn_mfma_f32_32x32x16_bf16(af[1][ks], bfr1, acc[UH][1][1], 0, 0, 0); \
        } } while (0)

    float pqv[2][2], wav[2][2];
    float4 s0a, s0b, s1a, s1b;   // A depth-2 reg slots

    // ---- prologue FIFO: [pqwa(8), A0(2), B0(4), A1(2), B1(4)] = 20
    //      vmcnt(6) drains pqwa+A0+B0, leaves [A1,B1] (entering state)
    #pragma unroll
    for (int uh = 0; uh < 2; ++uh)
        #pragma unroll
        for (int nf = 0; nf < 2; ++nf) {
            int u = uh * 256 + w * 64 + nf * 32 + lc;
            pqv[uh][nf] = pq[(size_t)b * Un + u];
            wav[uh][nf] = Wa[u];
        }
    SB();
    float4 p0 = *(const float4*)(gA);
    float4 p1 = *(const float4*)(gA + 4);
    SB();
    STAGE_B(0, 0, 0);
    SB();
    s1a = *(const float4*)(gA + 32);
    s1b = *(const float4*)(gA + 36);
    SB();
    STAGE_B(0, 1, 1);
    SB();
    asm volatile("s_waitcnt vmcnt(6)" ::: "memory");
    SB();
    *(bf16x8*)&Ah[0][awof] = cvt8(p0, p1);
    asm volatile("s_waitcnt lgkmcnt(0)" ::: "memory");
    __builtin_amdgcn_s_barrier();
    SB();

    #pragma unroll
    for (int kt = 0; kt < NKT; ++kt) {
        // ======== even phase (uh 0): MFMA reads Bh[(kt&1)<<1], Ah[kt&1]
        if (kt < NKT - 1) { STAGE_B(kt + 1, 0, ((kt + 1) & 1) << 1); SB(); }
        if (kt < NKT - 2) {
            const float* g = gA + (kt + 2) * 32;
            if ((kt & 1) == 0) { s0a = *(const float4*)(g); s0b = *(const float4*)(g + 4); }
            else               { s1a = *(const float4*)(g); s1b = *(const float4*)(g + 4); }
            SB();
        }
        READ_AF(kt & 1);
        MFMA_PH(0, (kt & 1) << 1);
        if (kt < NKT - 2)       PHASE_END(6);
        else if (kt == NKT - 2) PHASE_END(4);
        else                    PHASE_END(0);

        // ======== odd phase (uh 1): MFMA reads Bh[((kt&1)<<1)|1]
        if (kt < NKT - 1) { STAGE_B(kt + 1, 1, (((kt + 1) & 1) << 1) | 1); SB(); }
        MFMA_PH(1, ((kt & 1) << 1) | 1);
        if (kt < NKT - 1) {
            float4 pa, pb;
            if (((kt + 1) & 1) == 0) { pa = s0a; pb = s0b; }
            else                     { pa = s1a; pb = s1b; }
            *(bf16x8*)&Ah[(kt + 1) & 1][awof] = cvt8(pa, pb);
        }
        if (kt < NKT - 2)       PHASE_END(6);
        else if (kt == NKT - 2) PHASE_END(4);
        else { asm volatile("s_waitcnt lgkmcnt(0)" ::: "memory"); __builtin_amdgcn_s_barrier(); SB(); }
    }
    #undef STAGE_B
    #undef READ_AF
    #undef MFMA_PH

    // ---- epilogue: score = sum_u tanh(vals + pq[u]) * Wa[u]
    // C layout: col(u)=lc, row(t) = mf*32 + (r&3) + 8*(r>>2) + 4*l5
    #pragma unroll
    for (int mf = 0; mf < 2; ++mf) {
        #pragma unroll
        for (int r = 0; r < 16; ++r) {
            float s = 0.f;
            #pragma unroll
            for (int uh = 0; uh < 2; ++uh)
                #pragma unroll
                for (int nf = 0; nf < 2; ++nf)
                    s += tanh_fast(acc[uh][mf][nf][r] + pqv[uh][nf]) * wav[uh][nf];
            s += __shfl_xor(s, 16);
            s += __shfl_xor(s, 8);
            s += __shfl_xor(s, 4);
            s += __shfl_xor(s, 2);
            s += __shfl_xor(s, 1);
            if (lc == 0)
                sc_lds[w][mf * 32 + (r & 3) + 8 * (r >> 2) + 4 * l5] = s;
        }
    }
    __syncthreads();
    if (tid < TCH) {
        float v = (sc_lds[0][tid] + sc_lds[1][tid]) + (sc_lds[2][tid] + sc_lds[3][tid]);
        stot[tid] = v;
        score_out[(size_t)b * Tn + t0 + tid] = v;
    }
    __syncthreads();

    // ---- chunk softmax partials on wave 0
    if (tid < 64) {
        float v = stot[tid];
        float mx = v;
        #pragma unroll
        for (int off = 32; off; off >>= 1) mx = fmaxf(mx, __shfl_xor(mx, off));
        float e = __expf(v - mx);
        wexp[tid] = e;
        float sum = e;
        #pragma unroll
        for (int off = 32; off; off >>= 1) sum += __shfl_xor(sum, off);
        if (tid == 0) {
            pm[b * NCH + chunk] = mx;
            pl[b * NCH + chunk] = sum;
        }
    }
    __syncthreads();

    // ---- ctx partial: thread owns 2 m-cols; keys rows re-read (L2/L3-hot)
    const int c0 = tid * 2;
    const float* kp = keys + ((size_t)b * Tn + t0) * MSn + c0;
    float cx = 0.f, cy = 0.f;
    #pragma unroll 8
    for (int t = 0; t < TCH; ++t) {
        float2 kv = *(const float2*)(kp + (size_t)t * MSn);
        float wt = wexp[t];
        cx += wt * kv.x;
        cy += wt * kv.y;
    }
    float2 cacc = { cx, cy };
    *(float2*)&pctx[((size_t)(b * NCH + chunk)) * MSn + c0] = cacc;
}

// ---------------- merge chunk partials -> total_context ----------------
__global__ __launch_bounds__(512) void merge_kernel(const float* __restrict__ pm,
                                                    const float* __restrict__ pl,
                                                    const float* __restrict__ pctx,
                                                    float* __restrict__ ctx) {
    __shared__ float sm[NCH], sl[NCH];
    const int b = blockIdx.x, tid = threadIdx.x;
    if (tid < NCH) {
        sm[tid] = pm[b * NCH + tid];
        sl[tid] = pl[b * NCH + tid];
    }
    __syncthreads();
    float M = -1e30f;
    #pragma unroll
    for (int c = 0; c < NCH; ++c) M = fmaxf(M, sm[c]);
    float L = 0.f;
    #pragma unroll
    for (int c = 0; c < NCH; ++c) L += sl[c] * __expf(sm[c] - M);
    const float inv = 1.f / L;
    float acc = 0.f;
    #pragma unroll
    for (int c = 0; c < NCH; ++c)
        acc += __expf(sm[c] - M) * pctx[((size_t)(b * NCH + c)) * MSn + tid];
    ctx[(size_t)b * MSn + tid] = acc * inv;
}

extern "C" void kernel_launch(void* const* d_in, const int* in_sizes, int n_in,
                              void* d_out, int out_size, void* d_ws, size_t ws_size,
                              hipStream_t stream) {
    const float* query = (const float*)d_in[0];
    const float* keys  = (const float*)d_in[1];
    const float* Wq    = (const float*)d_in[2];
    const float* Wm    = (const float*)d_in[3];
    const float* Wa    = (const float*)d_in[4];

    float* ctx_out   = (float*)d_out;                    // [64][512]
    float* score_out = (float*)d_out + (size_t)Bn * MSn; // [64][2048]

    char* ws = (char*)d_ws;
    float* ws_pq   = (float*)(ws);                       // 128 KB
    unsigned short* ws_wmbf = (unsigned short*)(ws + 131072);  // 512 KB
    float* ws_pm   = (float*)(ws + 655360);              // 8 KB
    float* ws_pl   = (float*)(ws + 663552);              // 8 KB
    float* ws_pctx = (float*)(ws + 671744);              // 4 MB [64][32][512]

    cvt_kernel<<<(Un * MSn / 4) / 256, 256, 0, stream>>>(Wm, ws_wmbf);
    pq_kernel<<<dim3(Bn, 4), 128, 0, stream>>>(query, Wq, ws_pq);
    fused_kernel<<<dim3(NCH, Bn), 256, 0, stream>>>(keys, ws_wmbf, ws_pq, Wa,
                                                    score_out, ws_pm, ws_pl, ws_pctx);
    merge_kernel<<<Bn, 512, 0, stream>>>(ws_pm, ws_pl, ws_pctx, ctx_out);
}

// Round 15
// 174.674 us; speedup vs baseline: 1.1321x; 1.0937x over previous
//
#include <hip/hip_runtime.h>
#include <cstdint>
#include <cstddef>

#define Bn 64
#define Tn 2048
#define Un 512
#define QSn 512
#define MSn 512
#define TCH 64
#define NCH 32   // chunks per batch = Tn/TCH
#define NKT 16   // K-tiles: 512 / 32

using f32x16 = __attribute__((ext_vector_type(16))) float;
using bf16x8 = __attribute__((ext_vector_type(8))) short;

__device__ __forceinline__ unsigned short f2bf(float x) {
    unsigned int u = __float_as_uint(x);
    u += 0x7FFFu + ((u >> 16) & 1u);
    return (unsigned short)(u >> 16);
}

__device__ __forceinline__ unsigned int pk2bf(float lo, float hi) {
    unsigned int r;
    asm("v_cvt_pk_bf16_f32 %0, %1, %2" : "=v"(r) : "v"(lo), "v"(hi));
    return r;
}

__device__ __forceinline__ bf16x8 cvt8(float4 a, float4 b) {
    union { unsigned int u[4]; bf16x8 v; } r;
    r.u[0] = pk2bf(a.x, a.y);
    r.u[1] = pk2bf(a.z, a.w);
    r.u[2] = pk2bf(b.x, b.y);
    r.u[3] = pk2bf(b.z, b.w);
    return r.v;
}

__device__ __forceinline__ float tanh_fast(float x) {
    float e = exp2f(x * 2.885390043258667f);   // e^{2x}
    return 1.f - 2.f * __builtin_amdgcn_rcpf(e + 1.f);
}

// async global->LDS, 16B per lane; LDS dest = wave-uniform base + lane*16
#define GLOAD(G, L) __builtin_amdgcn_global_load_lds( \
    (const __attribute__((address_space(1))) void*)(G), \
    (__attribute__((address_space(3))) void*)(L), 16, 0, 0)

// ---------------- Wm f32 -> bf16 pre-convert ----------------
__global__ __launch_bounds__(256) void cvt_kernel(const float* __restrict__ src,
                                                  unsigned short* __restrict__ dst) {
    int i = blockIdx.x * 256 + threadIdx.x;  // one float4 per thread
    float4 v = *(const float4*)(src + (size_t)i * 4);
    ushort4 h = { f2bf(v.x), f2bf(v.y), f2bf(v.z), f2bf(v.w) };
    *(ushort4*)&dst[(size_t)i * 4] = h;
}

// ---------------- pq = query @ Wq^T : [B,U] ----------------
__global__ __launch_bounds__(128) void pq_kernel(const float* __restrict__ query,
                                                 const float* __restrict__ Wq,
                                                 float* __restrict__ pq) {
    __shared__ float ql[QSn];
    const int b = blockIdx.x;
    const int quad = blockIdx.y;
    const int tid = threadIdx.x;
    for (int i = tid; i < QSn; i += 128) ql[i] = query[(size_t)b * QSn + i];
    __syncthreads();
    const int u = quad * 128 + tid;
    const float* w = Wq + (size_t)u * QSn;
    float a0 = 0.f, a1 = 0.f;
    #pragma unroll 4
    for (int k = 0; k < QSn; k += 8) {
        float4 w0 = *(const float4*)(w + k);
        float4 w1 = *(const float4*)(w + k + 4);
        float4 q0 = *(const float4*)(ql + k);
        float4 q1 = *(const float4*)(ql + k + 4);
        a0 += w0.x * q0.x + w0.y * q0.y + w0.z * q0.z + w0.w * q0.w;
        a1 += w1.x * q1.x + w1.y * q1.y + w1.z * q1.z + w1.w * q1.w;
    }
    pq[(size_t)b * Un + u] = a0 + a1;
}

// ---------------- fused score+softmax+context (v15: TLP over pipelining) ----
// Block = (b, 64-t chunk), 512 thr = 8 waves. Wave w owns u [w*64, w*64+64):
// acc[2][2] = 64 AGPRs only -> __launch_bounds__(512,4) targets 2 blocks/CU
// (4 waves/SIMD). NO manual waits: textbook double-buffer + 2 __syncthreads
// per kt (m97's structure - the only one measured at 37% MfmaUtil). Overlap
// comes from co-resident waves, not manual FIFO counting.
// A: keys f32 reg-staged (load issued after barrier1, covered by MFMA phase;
//    cvt_pk + ds_write after barrier2). R11 zero-conflict row-pair swizzle.
// B: Wm bf16 GLOAD, 4/wave/kt, R11 source-folded swizzle. 74.5 KB LDS.
__global__ __launch_bounds__(512, 4) void fused_kernel(const float* __restrict__ keys,
                                                       const unsigned short* __restrict__ WmB,
                                                       const float* __restrict__ pq,
                                                       const float* __restrict__ Wa,
                                                       float* __restrict__ score_out,
                                                       float* __restrict__ pm,
                                                       float* __restrict__ pl,
                                                       float* __restrict__ pctx) {
    __shared__ __align__(16) unsigned short Ah[2][TCH * 32];    // 8 KB
    __shared__ __align__(16) unsigned short Bh[2][512 * 32];    // 64 KB
    __shared__ float sc_lds[8][TCH];                            // 2 KB
    __shared__ float stot[TCH];
    __shared__ float wexp[TCH];

    const int tid = threadIdx.x;
    const int lane = tid & 63;
    const int w = tid >> 6;
    const int lc = lane & 31;
    const int l5 = lane >> 5;
    const int b = blockIdx.y;
    const int chunk = blockIdx.x;
    const int t0 = chunk * TCH;

    // ---- A staging (threads 0..255 only; R14 formulas, R11-verified swizzle)
    const int ar = tid >> 2;          // 0..63 (t row)
    const int akg = tid & 3;          // granule of 8 f32
    const int awof = (tid >> 3) * 64 +
                     ((((akg << 1) | (ar & 1)) ^ ((tid >> 3) & 7)) * 8);
    const float* gA = keys + ((size_t)b * Tn + t0 + ar) * MSn + akg * 8;

    // ---- B staging source (R11-verbatim zero-conflict swizzle, wave-owned rows)
    const int bg = (lane & 7) ^ ((lane >> 3) & 7);
    const unsigned short* gBw = WmB +
        (size_t)(w * 64 + (((lane >> 3) << 1) | (bg & 1))) * MSn + (bg >> 1) * 8;

    f32x16 acc[2][2];
    #pragma unroll
    for (int mf = 0; mf < 2; ++mf)
        #pragma unroll
        for (int nf = 0; nf < 2; ++nf)
            #pragma unroll
            for (int r = 0; r < 16; ++r) acc[mf][nf][r] = 0.f;

    // ---- prologue: stage kt=0 into buffer 0
    {
        char* bD = (char*)&Bh[0][0] + w * 4096;
        #pragma unroll
        for (int j = 0; j < 4; ++j)
            GLOAD(gBw + (size_t)j * 16 * MSn, bD + j * 1024);
        if (tid < 256) {
            float4 p0 = *(const float4*)(gA);
            float4 p1 = *(const float4*)(gA + 4);
            *(bf16x8*)&Ah[0][awof] = cvt8(p0, p1);
        }
    }

    #pragma unroll
    for (int kt = 0; kt < NKT; ++kt) {
        __syncthreads();   // barrier1: staging of kt fully landed (full drain)

        // issue next A f32 loads EARLY; latency covered by this kt's MFMA
        float4 p0, p1;
        if (kt < NKT - 1 && tid < 256) {
            const float* g = gA + (kt + 1) * 32;
            p0 = *(const float4*)(g);
            p1 = *(const float4*)(g + 4);
        }

        // ---- MFMA phase on buffers[kt&1]
        {
            const unsigned short* lA = &Ah[kt & 1][0];
            const unsigned short* lB = &Bh[kt & 1][0];
            #pragma unroll
            for (int ks = 0; ks < 2; ++ks) {
                bf16x8 af[2], bfr[2];
                #pragma unroll
                for (int mf = 0; mf < 2; ++mf) {
                    int r = mf * 32 + lc;
                    int gp = (((ks * 2 + l5) << 1) | (r & 1)) ^ ((r >> 1) & 7);
                    af[mf] = *(const bf16x8*)&lA[(r >> 1) * 64 + gp * 8];
                }
                #pragma unroll
                for (int nf = 0; nf < 2; ++nf) {
                    int ru = w * 64 + nf * 32 + lc;
                    int gp = (((ks * 2 + l5) << 1) | (ru & 1)) ^ ((ru >> 1) & 7);
                    bfr[nf] = *(const bf16x8*)&Bh[kt & 1][(ru >> 1) * 64 + gp * 8];
                    (void)lB;
                }
                #pragma unroll
                for (int mf = 0; mf < 2; ++mf)
                    #pragma unroll
                    for (int nf = 0; nf < 2; ++nf)
                        acc[mf][nf] = __builtin_amdgcn_mfma_f32_32x32x16_bf16(
                            af[mf], bfr[nf], acc[mf][nf], 0, 0, 0);
            }
        }

        __syncthreads();   // barrier2: all reads of buffers[kt&1] done

        // ---- stage kt+1 into the other buffer
        if (kt < NKT - 1) {
            char* bD = (char*)&Bh[(kt + 1) & 1][0] + w * 4096;
            const unsigned short* gb = gBw + (kt + 1) * 32;
            #pragma unroll
            for (int j = 0; j < 4; ++j)
                GLOAD(gb + (size_t)j * 16 * MSn, bD + j * 1024);
            if (tid < 256)
                *(bf16x8*)&Ah[(kt + 1) & 1][awof] = cvt8(p0, p1);
        }
    }

    // ---- epilogue: score = sum_u tanh(vals + pq[u]) * Wa[u]
    // C layout: col(u)=lc, row(t) = mf*32 + (r&3) + 8*(r>>2) + 4*l5
    float pqv[2], wav[2];
    #pragma unroll
    for (int nf = 0; nf < 2; ++nf) {
        int u = w * 64 + nf * 32 + lc;
        pqv[nf] = pq[(size_t)b * Un + u];
        wav[nf] = Wa[u];
    }
    #pragma unroll
    for (int mf = 0; mf < 2; ++mf) {
        #pragma unroll
        for (int r = 0; r < 16; ++r) {
            float s = tanh_fast(acc[mf][0][r] + pqv[0]) * wav[0]
                    + tanh_fast(acc[mf][1][r] + pqv[1]) * wav[1];
            s += __shfl_xor(s, 16);
            s += __shfl_xor(s, 8);
            s += __shfl_xor(s, 4);
            s += __shfl_xor(s, 2);
            s += __shfl_xor(s, 1);
            if (lc == 0)
                sc_lds[w][mf * 32 + (r & 3) + 8 * (r >> 2) + 4 * l5] = s;
        }
    }
    __syncthreads();
    if (tid < TCH) {
        float v = ((sc_lds[0][tid] + sc_lds[1][tid]) + (sc_lds[2][tid] + sc_lds[3][tid]))
                + ((sc_lds[4][tid] + sc_lds[5][tid]) + (sc_lds[6][tid] + sc_lds[7][tid]));
        stot[tid] = v;
        score_out[(size_t)b * Tn + t0 + tid] = v;
    }
    __syncthreads();

    // ---- chunk softmax partials on wave 0
    if (tid < 64) {
        float v = stot[tid];
        float mx = v;
        #pragma unroll
        for (int off = 32; off; off >>= 1) mx = fmaxf(mx, __shfl_xor(mx, off));
        float e = __expf(v - mx);
        wexp[tid] = e;
        float sum = e;
        #pragma unroll
        for (int off = 32; off; off >>= 1) sum += __shfl_xor(sum, off);
        if (tid == 0) {
            pm[b * NCH + chunk] = mx;
            pl[b * NCH + chunk] = sum;
        }
    }
    __syncthreads();

    // ---- ctx partial: thread owns 1 m-col; keys rows re-read (L2/L3-hot)
    const float* kp = keys + ((size_t)b * Tn + t0) * MSn + tid;
    float cx = 0.f;
    #pragma unroll 8
    for (int t = 0; t < TCH; ++t)
        cx += wexp[t] * kp[(size_t)t * MSn];
    pctx[((size_t)(b * NCH + chunk)) * MSn + tid] = cx;
}

// ---------------- merge chunk partials -> total_context ----------------
__global__ __launch_bounds__(512) void merge_kernel(const float* __restrict__ pm,
                                                    const float* __restrict__ pl,
                                                    const float* __restrict__ pctx,
                                                    float* __restrict__ ctx) {
    __shared__ float sm[NCH], sl[NCH];
    const int b = blockIdx.x, tid = threadIdx.x;
    if (tid < NCH) {
        sm[tid] = pm[b * NCH + tid];
        sl[tid] = pl[b * NCH + tid];
    }
    __syncthreads();
    float M = -1e30f;
    #pragma unroll
    for (int c = 0; c < NCH; ++c) M = fmaxf(M, sm[c]);
    float L = 0.f;
    #pragma unroll
    for (int c = 0; c < NCH; ++c) L += sl[c] * __expf(sm[c] - M);
    const float inv = 1.f / L;
    float acc = 0.f;
    #pragma unroll
    for (int c = 0; c < NCH; ++c)
        acc += __expf(sm[c] - M) * pctx[((size_t)(b * NCH + c)) * MSn + tid];
    ctx[(size_t)b * MSn + tid] = acc * inv;
}

extern "C" void kernel_launch(void* const* d_in, const int* in_sizes, int n_in,
                              void* d_out, int out_size, void* d_ws, size_t ws_size,
                              hipStream_t stream) {
    const float* query = (const float*)d_in[0];
    const float* keys  = (const float*)d_in[1];
    const float* Wq    = (const float*)d_in[2];
    const float* Wm    = (const float*)d_in[3];
    const float* Wa    = (const float*)d_in[4];

    float* ctx_out   = (float*)d_out;                    // [64][512]
    float* score_out = (float*)d_out + (size_t)Bn * MSn; // [64][2048]

    char* ws = (char*)d_ws;
    float* ws_pq   = (float*)(ws);                       // 128 KB
    unsigned short* ws_wmbf = (unsigned short*)(ws + 131072);  // 512 KB
    float* ws_pm   = (float*)(ws + 655360);              // 8 KB
    float* ws_pl   = (float*)(ws + 663552);              // 8 KB
    float* ws_pctx = (float*)(ws + 671744);              // 4 MB [64][32][512]

    cvt_kernel<<<(Un * MSn / 4) / 256, 256, 0, stream>>>(Wm, ws_wmbf);
    pq_kernel<<<dim3(Bn, 4), 128, 0, stream>>>(query, Wq, ws_pq);
    fused_kernel<<<dim3(NCH, Bn), 512, 0, stream>>>(keys, ws_wmbf, ws_pq, Wa,
                                                    score_out, ws_pm, ws_pl, ws_pctx);
    merge_kernel<<<Bn, 512, 0, stream>>>(ws_pm, ws_pl, ws_pctx, ctx_out);
}

// Round 16
// 167.862 us; speedup vs baseline: 1.1781x; 1.0406x over previous
//
#include <hip/hip_runtime.h>
#include <cstdint>
#include <cstddef>

#define Bn 64
#define Tn 2048
#define Un 512
#define QSn 512
#define MSn 512
#define TCH 64
#define NCH 32   // chunks per batch = Tn/TCH
#define NKT 16   // K-tiles: 512 / 32

using f32x16 = __attribute__((ext_vector_type(16))) float;
using bf16x8 = __attribute__((ext_vector_type(8))) short;

__device__ __forceinline__ unsigned short f2bf(float x) {
    unsigned int u = __float_as_uint(x);
    u += 0x7FFFu + ((u >> 16) & 1u);
    return (unsigned short)(u >> 16);
}

__device__ __forceinline__ unsigned int pk2bf(float lo, float hi) {
    unsigned int r;
    asm("v_cvt_pk_bf16_f32 %0, %1, %2" : "=v"(r) : "v"(lo), "v"(hi));
    return r;
}

__device__ __forceinline__ float tanh_fast(float x) {
    float e = exp2f(x * 2.885390043258667f);   // e^{2x}
    return 1.f - 2.f * __builtin_amdgcn_rcpf(e + 1.f);
}

// async global->LDS, 16B per lane; LDS dest = wave-uniform base + lane*16
#define GLOAD(G, L) __builtin_amdgcn_global_load_lds( \
    (const __attribute__((address_space(1))) void*)(G), \
    (__attribute__((address_space(3))) void*)(L), 16, 0, 0)

#define SB() __builtin_amdgcn_sched_barrier(0)

// ---------------- Wm f32 -> bf16 pre-convert ----------------
__global__ __launch_bounds__(256) void cvt_kernel(const float* __restrict__ src,
                                                  unsigned short* __restrict__ dst) {
    int i = blockIdx.x * 256 + threadIdx.x;  // one float4 per thread
    float4 v = *(const float4*)(src + (size_t)i * 4);
    ushort4 h = { f2bf(v.x), f2bf(v.y), f2bf(v.z), f2bf(v.w) };
    *(ushort4*)&dst[(size_t)i * 4] = h;
}

// ---------------- pq = query @ Wq^T : [B,U] ----------------
__global__ __launch_bounds__(128) void pq_kernel(const float* __restrict__ query,
                                                 const float* __restrict__ Wq,
                                                 float* __restrict__ pq) {
    __shared__ float ql[QSn];
    const int b = blockIdx.x;
    const int quad = blockIdx.y;
    const int tid = threadIdx.x;
    for (int i = tid; i < QSn; i += 128) ql[i] = query[(size_t)b * QSn + i];
    __syncthreads();
    const int u = quad * 128 + tid;
    const float* w = Wq + (size_t)u * QSn;
    float a0 = 0.f, a1 = 0.f;
    #pragma unroll 4
    for (int k = 0; k < QSn; k += 8) {
        float4 w0 = *(const float4*)(w + k);
        float4 w1 = *(const float4*)(w + k + 4);
        float4 q0 = *(const float4*)(ql + k);
        float4 q1 = *(const float4*)(ql + k + 4);
        a0 += w0.x * q0.x + w0.y * q0.y + w0.z * q0.z + w0.w * q0.w;
        a1 += w1.x * q1.x + w1.y * q1.y + w1.z * q1.z + w1.w * q1.w;
    }
    pq[(size_t)b * Un + u] = a0 + a1;
}

// ---------------- fused score+softmax+context (v16: 1 lgkm-barrier/kt) ------
// Block = (b, 64-t chunk), 512 thr = 8 waves, wave w owns u [w*64, w*64+64):
// acc[2][2] = 64 AGPR. R15 geometry, restructured schedule:
//  head(kt): issue A(kt+1) flat (1 float4/thread, uniform FIFO) -> issue
//  B(kt+1) GLOADs (wave-private dbuf) -> vmcnt(5) [drains exactly B(kt),
//  leaves the 5 just-issued] -> lgkmcnt(0) -> raw s_barrier -> MFMA(kt) ->
//  tail: cvt_pk + swizzled ds_write_b64 of A(kt+1) (compiler-counted vmcnt,
//  WAVE-LOCAL stall after the barrier - no block convoy).
// Races: Ah WAR/RAW one-full-barrier separated; B wave-private; FIFO counts
// hand-traced incl. prologue + tails; pq/Wa in prologue regs (anti-hoist).
__global__ __launch_bounds__(512, 4) void fused_kernel(const float* __restrict__ keys,
                                                       const unsigned short* __restrict__ WmB,
                                                       const float* __restrict__ pq,
                                                       const float* __restrict__ Wa,
                                                       float* __restrict__ score_out,
                                                       float* __restrict__ pm,
                                                       float* __restrict__ pl,
                                                       float* __restrict__ pctx) {
    __shared__ __align__(16) unsigned short Ah[2][TCH * 32];    // 8 KB
    __shared__ __align__(16) unsigned short Bh[2][512 * 32];    // 64 KB
    __shared__ float sc_lds[8][TCH];                            // 2 KB
    __shared__ float stot[TCH];
    __shared__ float wexp[TCH];

    const int tid = threadIdx.x;
    const int lane = tid & 63;
    const int w = tid >> 6;
    const int lc = lane & 31;
    const int l5 = lane >> 5;
    const int b = blockIdx.y;
    const int chunk = blockIdx.x;
    const int t0 = chunk * TCH;

    // ---- A staging: ALL 512 threads, 1 float4 each (row ar, k-quad kq)
    const int ar = tid >> 3;          // 0..63
    const int kq = tid & 7;           // 4 f32 at k = kq*4
    // bf16 dest (rowpair layout, granule=8bf16=16B): rp=ar>>1,
    // logical g = ((kq>>1)<<1)|(ar&1), phys = g ^ (rp&7), half = kq&1
    const int awof = (ar >> 1) * 64 +
                     (((((kq >> 1) << 1) | (ar & 1)) ^ ((ar >> 1) & 7)) * 8) +
                     (kq & 1) * 4;
    const float* gA = keys + ((size_t)b * Tn + t0 + ar) * MSn + kq * 4;

    // ---- B staging source (R11/R15-verbatim zero-conflict swizzle)
    const int bg = (lane & 7) ^ ((lane >> 3) & 7);
    const unsigned short* gBw = WmB +
        (size_t)(w * 64 + (((lane >> 3) << 1) | (bg & 1))) * MSn + (bg >> 1) * 8;

    #define STAGE_B(KT, BUF) do { \
        const unsigned short* gb_ = gBw + (KT) * 32; \
        char* bD_ = (char*)&Bh[BUF][0] + w * 4096; \
        GLOAD(gb_,                    bD_); \
        GLOAD(gb_ + (size_t)16 * MSn, bD_ + 1024); \
        GLOAD(gb_ + (size_t)32 * MSn, bD_ + 2048); \
        GLOAD(gb_ + (size_t)48 * MSn, bD_ + 3072); } while (0)

    f32x16 acc[2][2];
    #pragma unroll
    for (int mf = 0; mf < 2; ++mf)
        #pragma unroll
        for (int nf = 0; nf < 2; ++nf)
            #pragma unroll
            for (int r = 0; r < 16; ++r) acc[mf][nf][r] = 0.f;

    // ---- prologue: pq/Wa regs; A(0); B(0); cvt+write A(0)
    float pqv[2], wav[2];
    #pragma unroll
    for (int nf = 0; nf < 2; ++nf) {
        int u = w * 64 + nf * 32 + lc;
        pqv[nf] = pq[(size_t)b * Un + u];
        wav[nf] = Wa[u];
    }
    SB();
    {
        float4 p = *(const float4*)(gA);
        SB();
        STAGE_B(0, 0);
        SB();
        uint2 h;
        h.x = pk2bf(p.x, p.y);
        h.y = pk2bf(p.z, p.w);
        *(uint2*)&Ah[0][awof] = h;   // compiler auto-waits A(0); B(0) stays out
    }

    #pragma unroll
    for (int kt = 0; kt < NKT; ++kt) {
        float4 p;
        if (kt < NKT - 1) {
            // head: issue A(kt+1) then B(kt+1)  (FIFO: [B(kt)4, A+1, B+1 x4])
            p = *(const float4*)(gA + (kt + 1) * 32);
            SB();
            STAGE_B(kt + 1, (kt + 1) & 1);
            SB();
            asm volatile("s_waitcnt vmcnt(5) lgkmcnt(0)" ::: "memory");  // B(kt) landed
        } else {
            asm volatile("s_waitcnt vmcnt(0) lgkmcnt(0)" ::: "memory");  // B(15) landed
        }
        __builtin_amdgcn_s_barrier();   // Ah[kt&1] writes visible; NO vm drain
        SB();

        // ---- MFMA(kt): Ah[kt&1] shared, Bh[kt&1] wave-private rows
        {
            const unsigned short* lA = &Ah[kt & 1][0];
            const unsigned short* lB = &Bh[kt & 1][0];
            #pragma unroll
            for (int ks = 0; ks < 2; ++ks) {
                bf16x8 af[2], bfr[2];
                #pragma unroll
                for (int mf = 0; mf < 2; ++mf) {
                    int r = mf * 32 + lc;
                    int gp = (((ks * 2 + l5) << 1) | (r & 1)) ^ ((r >> 1) & 7);
                    af[mf] = *(const bf16x8*)&lA[(r >> 1) * 64 + gp * 8];
                }
                #pragma unroll
                for (int nf = 0; nf < 2; ++nf) {
                    int ru = w * 64 + nf * 32 + lc;
                    int gp = (((ks * 2 + l5) << 1) | (ru & 1)) ^ ((ru >> 1) & 7);
                    bfr[nf] = *(const bf16x8*)&lB[(ru >> 1) * 64 + gp * 8];
                }
                #pragma unroll
                for (int mf = 0; mf < 2; ++mf)
                    #pragma unroll
                    for (int nf = 0; nf < 2; ++nf)
                        acc[mf][nf] = __builtin_amdgcn_mfma_f32_32x32x16_bf16(
                            af[mf], bfr[nf], acc[mf][nf], 0, 0, 0);
            }
        }
        SB();

        // tail: cvt + swizzled write A(kt+1) into the other Ah buffer.
        // (wave-local auto vmcnt(4) here; WAR safe: that buffer's readers
        // finished lgkm before they passed THIS kt's barrier.)
        if (kt < NKT - 1) {
            uint2 h;
            h.x = pk2bf(p.x, p.y);
            h.y = pk2bf(p.z, p.w);
            *(uint2*)&Ah[(kt + 1) & 1][awof] = h;
        }
    }
    #undef STAGE_B

    // ---- epilogue: score = sum_u tanh(vals + pq[u]) * Wa[u]
    // C layout: col(u)=lc, row(t) = mf*32 + (r&3) + 8*(r>>2) + 4*l5
    #pragma unroll
    for (int mf = 0; mf < 2; ++mf) {
        #pragma unroll
        for (int r = 0; r < 16; ++r) {
            float s = tanh_fast(acc[mf][0][r] + pqv[0]) * wav[0]
                    + tanh_fast(acc[mf][1][r] + pqv[1]) * wav[1];
            s += __shfl_xor(s, 16);
            s += __shfl_xor(s, 8);
            s += __shfl_xor(s, 4);
            s += __shfl_xor(s, 2);
            s += __shfl_xor(s, 1);
            if (lc == 0)
                sc_lds[w][mf * 32 + (r & 3) + 8 * (r >> 2) + 4 * l5] = s;
        }
    }
    __syncthreads();
    if (tid < TCH) {
        float v = ((sc_lds[0][tid] + sc_lds[1][tid]) + (sc_lds[2][tid] + sc_lds[3][tid]))
                + ((sc_lds[4][tid] + sc_lds[5][tid]) + (sc_lds[6][tid] + sc_lds[7][tid]));
        stot[tid] = v;
        score_out[(size_t)b * Tn + t0 + tid] = v;
    }
    __syncthreads();

    // ---- chunk softmax partials on wave 0
    if (tid < 64) {
        float v = stot[tid];
        float mx = v;
        #pragma unroll
        for (int off = 32; off; off >>= 1) mx = fmaxf(mx, __shfl_xor(mx, off));
        float e = __expf(v - mx);
        wexp[tid] = e;
        float sum = e;
        #pragma unroll
        for (int off = 32; off; off >>= 1) sum += __shfl_xor(sum, off);
        if (tid == 0) {
            pm[b * NCH + chunk] = mx;
            pl[b * NCH + chunk] = sum;
        }
    }
    __syncthreads();

    // ---- ctx partial: thread owns 1 m-col; keys rows re-read (L2/L3-hot)
    const float* kp = keys + ((size_t)b * Tn + t0) * MSn + tid;
    float cx = 0.f;
    #pragma unroll 8
    for (int t = 0; t < TCH; ++t)
        cx += wexp[t] * kp[(size_t)t * MSn];
    pctx[((size_t)(b * NCH + chunk)) * MSn + tid] = cx;
}

// ---------------- merge chunk partials -> total_context ----------------
__global__ __launch_bounds__(512) void merge_kernel(const float* __restrict__ pm,
                                                    const float* __restrict__ pl,
                                                    const float* __restrict__ pctx,
                                                    float* __restrict__ ctx) {
    __shared__ float sm[NCH], sl[NCH];
    const int b = blockIdx.x, tid = threadIdx.x;
    if (tid < NCH) {
        sm[tid] = pm[b * NCH + tid];
        sl[tid] = pl[b * NCH + tid];
    }
    __syncthreads();
    float M = -1e30f;
    #pragma unroll
    for (int c = 0; c < NCH; ++c) M = fmaxf(M, sm[c]);
    float L = 0.f;
    #pragma unroll
    for (int c = 0; c < NCH; ++c) L += sl[c] * __expf(sm[c] - M);
    const float inv = 1.f / L;
    float acc = 0.f;
    #pragma unroll
    for (int c = 0; c < NCH; ++c)
        acc += __expf(sm[c] - M) * pctx[((size_t)(b * NCH + c)) * MSn + tid];
    ctx[(size_t)b * MSn + tid] = acc * inv;
}

extern "C" void kernel_launch(void* const* d_in, const int* in_sizes, int n_in,
                              void* d_out, int out_size, void* d_ws, size_t ws_size,
                              hipStream_t stream) {
    const float* query = (const float*)d_in[0];
    const float* keys  = (const float*)d_in[1];
    const float* Wq    = (const float*)d_in[2];
    const float* Wm    = (const float*)d_in[3];
    const float* Wa    = (const float*)d_in[4];

    float* ctx_out   = (float*)d_out;                    // [64][512]
    float* score_out = (float*)d_out + (size_t)Bn * MSn; // [64][2048]

    char* ws = (char*)d_ws;
    float* ws_pq   = (float*)(ws);                       // 128 KB
    unsigned short* ws_wmbf = (unsigned short*)(ws + 131072);  // 512 KB
    float* ws_pm   = (float*)(ws + 655360);              // 8 KB
    float* ws_pl   = (float*)(ws + 663552);              // 8 KB
    float* ws_pctx = (float*)(ws + 671744);              // 4 MB [64][32][512]

    cvt_kernel<<<(Un * MSn / 4) / 256, 256, 0, stream>>>(Wm, ws_wmbf);
    pq_kernel<<<dim3(Bn, 4), 128, 0, stream>>>(query, Wq, ws_pq);
    fused_kernel<<<dim3(NCH, Bn), 512, 0, stream>>>(keys, ws_wmbf, ws_pq, Wa,
                                                    score_out, ws_pm, ws_pl, ws_pctx);
    merge_kernel<<<Bn, 512, 0, stream>>>(ws_pm, ws_pl, ws_pctx, ctx_out);
}